// Round 14
// baseline (621.840 us; speedup 1.0000x reference)
//
#include <hip/hip_runtime.h>

// MinkowskiBroadcast: out[p][c] = x_glob[batch_idx[p]][c]
//
// R12 measurement: bench = C + k*T; C ~ 411.5 us (harness re-poison),
// T ~ 104.6 us (kernel, ~4.9 TB/s). Pure-write floor ~82 us (fills at
// 6.28 TB/s). Last structural delta vs fills: WRITE LOCALITY — grid-stride
// (8 MB jumps per thread-iteration) sprays each block's stores across the
// whole buffer; fills write block-contiguous ranges.
//
// THIS ROUND: block-contiguous partitioning. Block b owns chunks
// [b*span, b*span+span) (span=15872 chunks ~ 248 KB, multiple of 256 so
// 32-lane groups share a point index). Consecutive lanes -> consecutive
// 16 B stores; per-block bidx slice ~2 KB contiguous. Keep LDS-staged
// x_glob + BATCH index prefetch (R10 structure) to isolate the mapping
// change. DOUBLE-LAUNCHED for measurability (ΔT x2 on bench metric):
//   locality helps: dur ~ 587-602; neutral ~620; regression >640.
// Next round ships the winner single-launch.

typedef float v4f __attribute__((ext_vector_type(4)));

#define BATCH 8

__global__ __launch_bounds__(256) void
minkowski_broadcast_kernel(const v4f* __restrict__ xg,   // [32*32] 16B quads
                           const int* __restrict__ bidx, // [N]
                           v4f*       __restrict__ out,  // [N*32]
                           int n_chunks, int span) {
    __shared__ v4f lds_xg[32 * 32];   // 16 KB: whole x_glob table
    for (int i = threadIdx.x; i < 32 * 32; i += 256)
        lds_xg[i] = xg[i];
    __syncthreads();

    const int wbase = (int)blockIdx.x * span;
    const int end   = min(wbase + span, n_chunks);

    // Initial index prefetch (g>>5 uniform per 32-lane group: wbase,
    // batch step are multiples of 256).
    int b[BATCH];
#pragma unroll
    for (int k = 0; k < BATCH; ++k) {
        int g = wbase + (int)threadIdx.x + k * 256;
        b[k] = (g < end) ? bidx[g >> 5] : 0;
    }

    for (int base = wbase + (int)threadIdx.x; base < end; base += BATCH * 256) {
        // Issue next batch's index loads BEFORE the stores (older than the
        // stores on vmcnt -> waits never drain the store queue).
        int bn[BATCH];
        const int nbase = base + BATCH * 256;
#pragma unroll
        for (int k = 0; k < BATCH; ++k) {
            int g = nbase + k * 256;
            bn[k] = (g < end) ? bidx[g >> 5] : 0;
        }
        // Gather from LDS (lgkmcnt) and stream block-contiguous stores.
#pragma unroll
        for (int k = 0; k < BATCH; ++k) {
            int g = base + k * 256;
            if (g < end)
                out[g] = lds_xg[(b[k] << 5) + (g & 31)];
        }
#pragma unroll
        for (int k = 0; k < BATCH; ++k) b[k] = bn[k];
    }
}

extern "C" void kernel_launch(void* const* d_in, const int* in_sizes, int n_in,
                              void* d_out, int out_size, void* d_ws, size_t ws_size,
                              hipStream_t stream) {
    const v4f* xg   = (const v4f*)d_in[0];  // x_glob [32][128] f32
    const int* bidx = (const int*)d_in[1];  // batch_idx [N] i32
    v4f*       out  = (v4f*)d_out;          // [N][128] f32

    const int n_chunks = out_size / 4;      // 16B chunks (N * 128 / 4)

    const int block = 256;
    const int grid  = 2048;
    // span: ceil(n_chunks/grid) rounded up to a multiple of block (256).
    const int span  = ((n_chunks / grid + block - 1) / block) * block;

    // MEASUREMENT: two identical idempotent launches -> dur = C + 2T.
    minkowski_broadcast_kernel<<<grid, block, 0, stream>>>(xg, bidx, out, n_chunks, span);
    minkowski_broadcast_kernel<<<grid, block, 0, stream>>>(xg, bidx, out, n_chunks, span);
}